// Round 3
// baseline (151.166 us; speedup 1.0000x reference)
//
#include <hip/hip_runtime.h>

// rosa_4bit_layer: causal linear attention with per-head 4x4 state.
//   S_t = S_{t-1} + k_t v_t^T ;  o_t = q_t^T S_t ;  out = o * emb
// Shapes: x{q,k,v}: (B=4, T=4096, C=512) fp32, emb: (1,1,512) fp32.
// H = C/4 = 128 heads, head_dim = 4. Heads are contiguous 4-float groups in C.
//
// Strategy: chunked associative scan over T.
//   Kernel A: per-chunk sums of k (outer) v per head  -> partials in d_ws
//   Kernel B: exclusive prefix scan of partials over chunks (in-place)
//   Kernel C: replay each chunk from its start state, write output.
// State stored column-major: partial[...][e*4+d] = S[d][e], so each thread
// (h,e) owns one float4 column (the e-th column of S for head h).

constexpr int B  = 4;
constexpr int T  = 4096;
constexpr int C  = 512;
constexpr int CT = 32;     // timesteps per chunk
constexpr int NC = T / CT; // 128 chunks per sequence
// partial layout (floats): ((b*NC + c)*128 + h)*16 + e*4 + d   -> 4 MiB total
// (d_ws must hold B*NC*2048 floats = 4 MiB; harness ws_size is larger.)

__global__ __launch_bounds__(512) void k_partial(const float* __restrict__ k,
                                                 const float* __restrict__ v,
                                                 float* __restrict__ part) {
  const int bc  = blockIdx.x;            // b*NC + c
  const int b   = bc / NC;
  const int c   = bc % NC;
  const int tid = threadIdx.x;           // 0..511
  const int h   = tid >> 2;
  const int e   = tid & 3;
  const int t0  = c * CT;

  const size_t base = ((size_t)b * T + t0) * (size_t)C + (h << 2);
  const float* kb = k + base;
  const float* vb = v + base + e;

  float4 acc = {0.f, 0.f, 0.f, 0.f};
#pragma unroll 8
  for (int t = 0; t < CT; ++t) {
    const float4 k4 = *reinterpret_cast<const float4*>(kb + (size_t)t * C);
    const float  ve = vb[(size_t)t * C];
    acc.x += k4.x * ve;
    acc.y += k4.y * ve;
    acc.z += k4.z * ve;
    acc.w += k4.w * ve;
  }
  // flat float4 index: bc*512 + tid  (== (bc*2048 + tid*4)/4)
  reinterpret_cast<float4*>(part)[(size_t)bc * 512 + tid] = acc;
}

__global__ __launch_bounds__(256) void k_scan(float* __restrict__ part) {
  // 8 blocks per b; thread j in [0, 2048) = h*16 + e*4 + d
  const int b = blockIdx.x >> 3;
  const int j = ((blockIdx.x & 7) << 8) + threadIdx.x;
  float run = 0.f;
  for (int c = 0; c < NC; ++c) {
    float* p = part + (size_t)(b * NC + c) * 2048 + j;
    const float val = *p;
    *p = run;        // exclusive prefix (state at chunk start)
    run += val;
  }
}

__global__ __launch_bounds__(512) void k_out(const float* __restrict__ q,
                                             const float* __restrict__ k,
                                             const float* __restrict__ v,
                                             const float* __restrict__ emb,
                                             const float* __restrict__ part,
                                             float* __restrict__ out) {
  const int bc  = blockIdx.x;
  const int b   = bc / NC;
  const int c   = bc % NC;
  const int tid = threadIdx.x;
  const int h   = tid >> 2;
  const int e   = tid & 3;
  const int t0  = c * CT;

  const size_t base = ((size_t)b * T + t0) * (size_t)C + (h << 2);
  const float* qb = q + base;
  const float* kb = k + base;
  const float* vb = v + base + e;
  float*       ob = out + base + e;

  float4 S = reinterpret_cast<const float4*>(part)[(size_t)bc * 512 + tid];
  const float embv = emb[(h << 2) + e];

#pragma unroll 8
  for (int t = 0; t < CT; ++t) {
    const float4 k4 = *reinterpret_cast<const float4*>(kb + (size_t)t * C);
    const float4 q4 = *reinterpret_cast<const float4*>(qb + (size_t)t * C);
    const float  ve = vb[(size_t)t * C];
    S.x += k4.x * ve;
    S.y += k4.y * ve;
    S.z += k4.z * ve;
    S.w += k4.w * ve;
    const float o = q4.x * S.x + q4.y * S.y + q4.z * S.z + q4.w * S.w;
    ob[(size_t)t * C] = o * embv;
  }
}

extern "C" void kernel_launch(void* const* d_in, const int* in_sizes, int n_in,
                              void* d_out, int out_size, void* d_ws, size_t ws_size,
                              hipStream_t stream) {
  const float* xq  = (const float*)d_in[0];
  const float* xk  = (const float*)d_in[1];
  const float* xv  = (const float*)d_in[2];
  const float* emb = (const float*)d_in[3];
  float* out  = (float*)d_out;
  float* part = (float*)d_ws;   // B*NC*2048 floats = 4 MiB

  k_partial<<<B * NC, 512, 0, stream>>>(xk, xv, part);
  k_scan<<<B * 8, 256, 0, stream>>>(part);
  k_out<<<B * NC, 512, 0, stream>>>(xq, xk, xv, emb, part, out);
}